// Round 15
// baseline (95.514 us; speedup 1.0000x reference)
//
#include <hip/hip_runtime.h>
#include <hip/hip_bf16.h>
#include <cstdint>
#include <cstddef>
#include <math.h>

// Problem constants (reference: B=4096, D=256, T=0.5)
#define BSZ   4096
#define NROW  8192          // 2*B
#define DIM   256
#define INV_T 2.0f
#define EPS_N 1e-8f

typedef __attribute__((ext_vector_type(4))) float f32x4;

// async global->LDS 16B helper (wave-uniform LDS base + lane*16 layout)
__device__ __forceinline__ void load_lds16(const void* g, void* l) {
    __builtin_amdgcn_global_load_lds(
        (const __attribute__((address_space(1))) void*)g,
        (__attribute__((address_space(3))) void*)l,
        16, 0, 0);
}

#define VMWAIT(N) asm volatile("s_waitcnt vmcnt(" #N ")" ::: "memory")

// ---------------------------------------------------------------------------
// zn3 staged layout (R11/R13-verified fp8 e4m3):
//   [strip(64)][kc(4)][row(128)][slot8(8)], 8-byte units, XOR swizzle baked:
//   zn3[s][kc][row][u] holds elements kc*64 + (u^(row&7))*8 .. +8
//
// Kernel 1: row-normalize concat(z1,z2) into fp8 zn3 (R11-verified).
// Also resets the finalize ticket counter.
__global__ __launch_bounds__(256)
void nt_normalize(const float* __restrict__ z1,
                  const float* __restrict__ z2,
                  char* __restrict__ zn3,
                  unsigned int* __restrict__ cnt) {
    const int wave = threadIdx.x >> 6;
    const int lane = threadIdx.x & 63;
    const int row  = blockIdx.x * 4 + wave;
    const float* src = (row < BSZ) ? (z1 + (size_t)row * DIM)
                                   : (z2 + (size_t)(row - BSZ) * DIM);
    const float4 v = ((const float4*)src)[lane];
    float ss = v.x * v.x + v.y * v.y + v.z * v.z + v.w * v.w;
    #pragma unroll
    for (int off = 32; off; off >>= 1) ss += __shfl_xor(ss, off);
    const float rinv = 1.0f / fmaxf(sqrtf(ss), EPS_N);  // torch eps clamp
    int pk = 0;
    pk = __builtin_amdgcn_cvt_pk_fp8_f32(v.x * rinv, v.y * rinv, pk, false);
    pk = __builtin_amdgcn_cvt_pk_fp8_f32(v.z * rinv, v.w * rinv, pk, true);
    // lane i holds elements k = 4i..4i+3: kc=i>>4, slot8=(i>>1)&7, off=(i&1)*4
    const int s    = row >> 7;
    const int lrow = row & 127;
    const int kc   = lane >> 4;
    const int unit = (lane >> 1) & 7;
    const int off4 = (lane & 1) * 4;
    const int u    = unit ^ (lrow & 7);          // baked swizzle
    *(int*)(zn3 + (size_t)s * 32768 + kc * 8192 + lrow * 64 + u * 8 + off4) = pk;
    if (row == 0 && lane == 0) *cnt = 0;         // reset finalize ticket
}

// ---------------------------------------------------------------------------
// Kernel 2: tiled Zn·Znᵀ, 256x128 tiles (1056 blocks: A-strip I of 256 rows
// paired with one 128-col B-strip j >= 2I), 512 threads = 8 waves of 64x64
// (the verified R13 per-wave geometry). Each block covers TWO vertically
// adjacent 128-tiles sharing the A strip: staged bytes 96 KB per 2 tiles
// (vs 128 KB) -> 101 MB total (-24%), half the prologues/launches.
// K-pipeline = R14's counted-vmcnt dbuf with 3-load stages. Epilogue =
// R13's verbatim with bi -> bi_w = 2I + (wrow>=128); ragged-edge handled by
// wave predicates: skip (bi_w > j, slots covered by neighbor tile's
// col-side) and diag (bi_w == j). Slot coverage: row in strip s gets slots
// 0..2s-1 from col-sides (bi_w<s), 2s..127 from row-sides (j>=s) — each
// written exactly once, no init, no atomics.
__global__ __launch_bounds__(512)
void nt_gram(const char* __restrict__ zn3,
             float* __restrict__ part,
             float* __restrict__ pos) {
    // Decode block -> (I, j): C(I) = I*(65-I) tiles precede A-strip I.
    const int p = blockIdx.x;
    int I = (int)((65.0 - sqrt(4225.0 - 4.0 * (double)p)) * 0.5);
    while ((I + 1) * (65 - (I + 1)) <= p) ++I;   // fp-edge correction
    while (I * (65 - I) > p) --I;
    const int j = 2 * I + (p - I * (65 - I));

    __shared__ char lds[49152];   // dbuf x { A.h0 8K | A.h1 8K | B 8K }

    const int t    = threadIdx.x;
    const int lane = t & 63;
    const int wave = t >> 6;
    const int wrow = (wave >> 1) * 64;   // 0,64,128,192
    const int wcol = (wave & 1) * 64;    // 0,64
    const int q    = lane >> 4;
    const int r16  = lane & 15;
    const int sw   = r16 & 7;            // swizzle key (== row&7)
    const int t16  = t * 16;
    const int ahalf = (wrow >> 7) * 8192;  // which A half this wave reads
    const int lw    = wrow & 64;           // row offset within the half

    const char* Ah0  = zn3 + (size_t)(2 * I) * 32768;
    const char* Ah1  = zn3 + (size_t)(2 * I + 1) * 32768;
    const char* Bsrc = zn3 + (size_t)j * 32768;

    f32x4 acc[4][4] = {};

    // Stage kc into buf: 3 DMA loads/thread (A.h0, A.h1, B — 8 KB streams).
#define STAGE(kc, buf)                                                   \
    {                                                                    \
        char* d_ = lds + (buf) * 24576;                                  \
        load_lds16(Ah0 + (kc) * 8192 + t16,  d_ + t16);                  \
        load_lds16(Ah1 + (kc) * 8192 + t16,  d_ + 8192 + t16);           \
        load_lds16(Bsrc + (kc) * 8192 + t16, d_ + 16384 + t16);          \
    }

#define COMPUTE(buf)                                                     \
    {                                                                    \
        const char* Aw = lds + (buf) * 24576 + ahalf;                    \
        const char* Bw = lds + (buf) * 24576 + 16384;                    \
        _Pragma("unroll")                                                \
        for (int kh = 0; kh < 2; ++kh) {                                 \
            const int spos = (((kh << 2) + q) ^ sw) << 3;                \
            long af[4], bfv[4];                                          \
            _Pragma("unroll")                                            \
            for (int mi = 0; mi < 4; ++mi)                               \
                af[mi] = *(const long*)(Aw + (lw + mi * 16 + r16) * 64 + spos); \
            _Pragma("unroll")                                            \
            for (int ni = 0; ni < 4; ++ni)                               \
                bfv[ni] = *(const long*)(Bw + (wcol + ni * 16 + r16) * 64 + spos); \
            _Pragma("unroll")                                            \
            for (int mi = 0; mi < 4; ++mi)                               \
                _Pragma("unroll")                                        \
                for (int ni = 0; ni < 4; ++ni)                           \
                    acc[mi][ni] = __builtin_amdgcn_mfma_f32_16x16x32_fp8_fp8( \
                        af[mi], bfv[ni], acc[mi][ni], 0, 0, 0);          \
        }                                                                \
    }

    // R14's proven ledger with 3-load stages: 3,6 -> wait3 -> 6 -> wait3
    // -> 6 -> wait3 -> wait0. No mid-loop drain.
    STAGE(0, 0)
    STAGE(1, 1)
    VMWAIT(3);
    __builtin_amdgcn_s_barrier();
    COMPUTE(0)
    __builtin_amdgcn_s_barrier();            // all waves done reading buf0
    __builtin_amdgcn_sched_barrier(0);
    STAGE(2, 0)
    VMWAIT(3);
    __builtin_amdgcn_s_barrier();
    COMPUTE(1)
    __builtin_amdgcn_s_barrier();            // all waves done reading buf1
    __builtin_amdgcn_sched_barrier(0);
    STAGE(3, 1)
    VMWAIT(3);
    __builtin_amdgcn_s_barrier();
    COMPUTE(0)
    VMWAIT(0);
    __builtin_amdgcn_s_barrier();
    COMPUTE(1)
#undef STAGE
#undef COMPUTE

    // Epilogue (R13-verified per-wave code; bi -> bi_w, wrow -> lw).
    const int  bi_w = 2 * I + (wrow >> 7);   // this wave's 128-tile row strip
    const bool skip = (bi_w > j);            // lower-tri sub-tile: contribute 0
    const bool diag = (bi_w == j);
    const int  c     = r16;
    const int  rslot = 2 * j + (wcol >> 6);
    const int  cslot = 2 * bi_w + (lw >> 6);
    float colp[4] = {0.f, 0.f, 0.f, 0.f};

    if (!skip) {
        #pragma unroll
        for (int mi = 0; mi < 4; ++mi) {
            #pragma unroll
            for (int r = 0; r < 4; ++r) {
                const int grow = bi_w * 128 + lw + mi * 16 + q * 4 + r;
                float s = 0.f;
                #pragma unroll
                for (int ni = 0; ni < 4; ++ni) {
                    const int gcol = j * 128 + wcol + ni * 16 + c;
                    const float val = acc[mi][ni][r];
                    float e = __expf(val * INV_T);
                    e = (grow == gcol) ? 0.f : e;   // exact diagonal exclusion
                    s += e;
                    colp[ni] += e;
                    if (gcol == grow + BSZ) {       // positive pair (j==bi_w+32)
                        pos[grow] = val;
                        pos[gcol] = val;            // symmetric partner
                    }
                }
                s += __shfl_xor(s, 1);
                s += __shfl_xor(s, 2);
                s += __shfl_xor(s, 4);
                s += __shfl_xor(s, 8);
                // Private half-slot: plain store, no atomic, no collision.
                if (c == 0) part[(size_t)grow * 128 + rslot] = s;
            }
        }
        // Col sums -> strip-j rows at this wave's private half-slot.
        if (!diag) {
            #pragma unroll
            for (int ni = 0; ni < 4; ++ni) {
                float cs = colp[ni];
                cs += __shfl_xor(cs, 16);
                cs += __shfl_xor(cs, 32);      // butterfly: wave total everywhere
                if (q == 0)
                    part[(size_t)(j * 128 + wcol + ni * 16 + c) * 128 + cslot] = cs;
            }
        }
    }
}

// ---------------------------------------------------------------------------
// Kernel 3: 64 blocks x 256 threads (R13-verified); block b reduces rows
// b*128..+127 of part[8192][128], per-row lse contribution, block-reduce;
// last block (ticket) folds the 64 block sums.
__global__ __launch_bounds__(256)
void nt_finalize(const float* __restrict__ part,
                 const float* __restrict__ pos,
                 float* __restrict__ blocksum,
                 unsigned int* __restrict__ cnt,
                 float* __restrict__ out) {
    const int b    = blockIdx.x;
    const int t    = threadIdx.x;
    const int lane = t & 63;
    const int row  = b * 128 + (t >> 1);
    const int half = t & 1;

    const float4* p4 = (const float4*)(part + (size_t)row * 128 + half * 64);
    float s = 0.f;
    #pragma unroll
    for (int j = 0; j < 16; ++j) {
        const float4 v = p4[j];
        s += v.x + v.y + v.z + v.w;
    }
    s += __shfl_xor(s, 1);                 // combine the two halves
    float contrib = 0.f;
    if (half == 0) {
        const float pl = pos[row] * INV_T;
        contrib = logf(__expf(pl) + s) - pl;
    }
    #pragma unroll
    for (int off = 32; off; off >>= 1) contrib += __shfl_xor(contrib, off);
    __shared__ float r4[4];
    __shared__ int   slast;
    if (lane == 0) r4[t >> 6] = contrib;
    __syncthreads();
    if (t == 0) {
        blocksum[b] = r4[0] + r4[1] + r4[2] + r4[3];
        __threadfence();
        slast = (atomicAdd(cnt, 1u) == 63u);
    }
    __syncthreads();
    if (slast && t < 64) {                 // last block: fold 64 block sums
        float v = atomicAdd(&blocksum[t], 0.0f);   // device-coherent read
        #pragma unroll
        for (int off = 32; off; off >>= 1) v += __shfl_xor(v, off);
        if (t == 0) out[0] = v * (1.0f / NROW);
    }
}

// ---------------------------------------------------------------------------
extern "C" void kernel_launch(void* const* d_in, const int* in_sizes, int n_in,
                              void* d_out, int out_size, void* d_ws, size_t ws_size,
                              hipStream_t stream) {
    const float* z1 = (const float*)d_in[0];
    const float* z2 = (const float*)d_in[1];
    float* out = (float*)d_out;

    // Workspace (~6.03 MB of the 256 MiB ws):
    char*  zn3      = (char*)d_ws;                                   // 2 MB
    float* part     = (float*)((char*)d_ws + (size_t)2097152);       // 4 MB
    float* pos      = (float*)((char*)d_ws + (size_t)6291456);       // 32 KB
    float* blocksum = pos + NROW;                                    // 256 B
    unsigned int* cnt = (unsigned int*)(blocksum + 64);              // 4 B

    nt_normalize<<<NROW / 4, 256, 0, stream>>>(z1, z2, zn3, cnt);
    nt_gram<<<1056, 512, 0, stream>>>(zn3, part, pos);
    nt_finalize<<<64, 256, 0, stream>>>(part, pos, blocksum, cnt, out);
}